// Round 2
// baseline (676.728 us; speedup 1.0000x reference)
//
#include <hip/hip_runtime.h>
#include <hip/hip_bf16.h>
#include <math.h>

// Segment-prefix max over [2048 segs x 512 rows x 128 fp32]; reduce max over
// first (size - window + 1) rows of each segment. Memory-bound: ~535 MB read.
// Roofline @6.3 TB/s ~ 85 us. R1 observation: dur_us includes ~500 us of
// harness reset traffic (2 GB ws poison + 512 MB x restore); kernel itself
// was <330 us. R2 change: per-segment row-phase stagger to break the 256 KB
// power-of-two inter-block stride (HBM channel camping) -- max is
// order-independent, so visiting rows in rotated order is free.

#define BLOCK 256

__device__ __forceinline__ float4 fmax4(float4 a, float4 b) {
    return make_float4(fmaxf(a.x, b.x), fmaxf(a.y, b.y),
                       fmaxf(a.z, b.z), fmaxf(a.w, b.w));
}

__global__ __launch_bounds__(BLOCK)
void seg_prefix_max_kernel(const float* __restrict__ x,
                           const int* __restrict__ sizes,
                           const int* __restrict__ wptr,
                           float* __restrict__ out,
                           int n_seg, int D) {
    const int seg = blockIdx.x;
    const int tid = threadIdx.x;
    const int w   = *wptr;

    // ---- start_i = sum(sizes[0..seg)) : strided sum + LDS tree reduce ----
    __shared__ int red[BLOCK];
    int partial = 0;
    for (int j = tid; j < seg; j += BLOCK) partial += sizes[j];
    red[tid] = partial;
    __syncthreads();
    for (int s = BLOCK / 2; s > 0; s >>= 1) {
        if (tid < s) red[tid] += red[tid + s];
        __syncthreads();
    }
    const long long start = red[0];
    const int L = sizes[seg] - w + 1;         // rows to reduce (510 here)

    // ---- strided max over rows; 32 x float4 lanes cover D=128 ----
    const int nc4  = D >> 2;                  // float4s per row (32)
    const int col4 = tid & 31;
    const int rg   = tid >> 5;                // 0..7 row groups

    float4 acc = make_float4(-INFINITY, -INFINITY, -INFINITY, -INFINITY);

    if (col4 < nc4 && L > 0) {
        // Per-segment rotation of row order: r -> (r + off) mod L.
        // Bijective over each thread's row set, so the union still covers
        // all rows exactly once; max is order-independent.
        const int off = (int)(((unsigned)seg * 2654435761u) % (unsigned)L);
        const float4* xb = (const float4*)x + (size_t)start * nc4 + col4;
        #pragma unroll 4
        for (int r = rg; r < L; r += 8) {
            int rr = r + off;
            rr = (rr >= L) ? (rr - L) : rr;   // wrap (predicated select)
            acc = fmax4(acc, xb[(size_t)rr * nc4]);
        }
    }

    // ---- reduce the 8 row-group partials via LDS ----
    __shared__ float4 part[8][32];
    if (col4 < nc4) part[rg][col4] = acc;
    __syncthreads();

    if (tid < nc4) {
        float4 a = part[0][tid];
        #pragma unroll
        for (int j = 1; j < 8; ++j) a = fmax4(a, part[j][tid]);
        ((float4*)out)[(size_t)seg * nc4 + tid] = a;
    }
}

extern "C" void kernel_launch(void* const* d_in, const int* in_sizes, int n_in,
                              void* d_out, int out_size, void* d_ws, size_t ws_size,
                              hipStream_t stream) {
    const float* x     = (const float*)d_in[0];
    const int*   sizes = (const int*)d_in[1];
    const int*   wptr  = (const int*)d_in[2];
    float*       out   = (float*)d_out;

    const int n_seg = in_sizes[1];            // 2048
    const int D     = out_size / n_seg;       // 128

    seg_prefix_max_kernel<<<n_seg, BLOCK, 0, stream>>>(x, sizes, wptr, out, n_seg, D);
}